// Round 1
// baseline (284.152 us; speedup 1.0000x reference)
//
#include <hip/hip_runtime.h>
#include <stdint.h>

// Problem constants (fixed by reference):
#define DIN   768
#define NPROJ 1536           // HID*OUT*2 = 64*12*2
#define SEQ   512
#define NHEAD 12
#define NBATCH 16
#define NEGV  1000000000000.0f

typedef short bf16x8 __attribute__((ext_vector_type(8)));
typedef float f32x4  __attribute__((ext_vector_type(4)));

__device__ __forceinline__ unsigned short f2bf(float f) {
    union { float f; unsigned int u; } v; v.f = f;
    return (unsigned short)((v.u + 0x7FFFu + ((v.u >> 16) & 1u)) >> 16);  // RTNE
}
__device__ __forceinline__ float bf2f(unsigned int u) {
    union { unsigned int u; float f; } v; v.u = u << 16;
    return v.f;
}

// ---- 1) Wt[n][k] = bf16(W[k][n]) : transposed so GEMM B-frags read contiguous K ----
__global__ void k_wt(const float* __restrict__ W, unsigned short* __restrict__ Wt) {
    __shared__ float tile[32][33];
    int n0 = blockIdx.x * 32, k0 = blockIdx.y * 32;
    int tx = threadIdx.x, ty = threadIdx.y;
    tile[ty][tx] = W[(size_t)(k0 + ty) * NPROJ + n0 + tx];
    __syncthreads();
    Wt[(size_t)(n0 + ty) * DIN + k0 + tx] = f2bf(tile[tx][ty]);
}

// ---- 2) P[m][n] = bf16( sum_k x[m][k]*W[k][n] + b[n] ), 128x128 tile, bf16 MFMA ----
__global__ __launch_bounds__(256) void k_gemm(const float* __restrict__ X,
                                              const unsigned short* __restrict__ Wt,
                                              const float* __restrict__ bias,
                                              unsigned short* __restrict__ P) {
    // 72-short row stride: 144 B = 36 banks -> only 2-way (free) conflicts on ds_read_b128
    __shared__ unsigned short sA[128][72];
    __shared__ unsigned short sB[128][72];
    const int tid = threadIdx.x;
    const int m0 = blockIdx.y * 128, n0 = blockIdx.x * 128;
    const int lane = tid & 63, w = tid >> 6;
    const int q = lane >> 4, r = lane & 15;
    const int wm = w >> 1, wn = w & 1;
    f32x4 acc[4][4];
#pragma unroll
    for (int i = 0; i < 4; i++)
#pragma unroll
        for (int j = 0; j < 4; j++) acc[i][j] = (f32x4){0.f, 0.f, 0.f, 0.f};

    for (int k0 = 0; k0 < DIN; k0 += 64) {
        __syncthreads();
        // stage A: 128x64, fp32 -> bf16 on the fly
#pragma unroll
        for (int it = 0; it < 8; it++) {
            int c = tid + it * 256;
            int row = c >> 4, col = (c & 15) * 4;
            float4 v = *(const float4*)&X[(size_t)(m0 + row) * DIN + k0 + col];
            short4 sv;
            sv.x = (short)f2bf(v.x); sv.y = (short)f2bf(v.y);
            sv.z = (short)f2bf(v.z); sv.w = (short)f2bf(v.w);
            *(short4*)&sA[row][col] = sv;
        }
        // stage B: 128x64 bf16 (already transposed)
#pragma unroll
        for (int it = 0; it < 4; it++) {
            int c = tid + it * 256;
            int row = c >> 3, col = (c & 7) * 8;
            *(int4*)&sB[row][col] = *(const int4*)&Wt[(size_t)(n0 + row) * DIN + k0 + col];
        }
        __syncthreads();
#pragma unroll
        for (int kk = 0; kk < 64; kk += 32) {
            bf16x8 af[4], bfr[4];
#pragma unroll
            for (int t = 0; t < 4; t++)
                af[t] = *(const bf16x8*)&sA[wm * 64 + t * 16 + r][kk + q * 8];
#pragma unroll
            for (int t = 0; t < 4; t++)
                bfr[t] = *(const bf16x8*)&sB[wn * 64 + t * 16 + r][kk + q * 8];
#pragma unroll
            for (int tm = 0; tm < 4; tm++)
#pragma unroll
                for (int tn = 0; tn < 4; tn++)
                    acc[tm][tn] = __builtin_amdgcn_mfma_f32_16x16x32_bf16(
                        af[tm], bfr[tn], acc[tm][tn], 0, 0, 0);
        }
    }
    // epilogue: +bias, store bf16. D layout: row=q*4+i, col=r  [m89/m91 verified]
#pragma unroll
    for (int tn = 0; tn < 4; tn++) {
        int gn = n0 + wn * 64 + tn * 16 + r;
        float bb = bias[gn];
#pragma unroll
        for (int tm = 0; tm < 4; tm++) {
            int gm = m0 + wm * 64 + tm * 16 + q * 4;
#pragma unroll
            for (int i = 0; i < 4; i++)
                P[(size_t)(gm + i) * NPROJ + gn] = f2bf(acc[tm][tn][i] + bb);
        }
    }
}

// ---- 3) in-place RoPE on P. Pair (d even, d+1); cos/sin idx = (d&31), (d&31)+1.
// One thread per (row, even-freq): 2 sincos amortized over 24 vectors x 2 d-positions.
__global__ void k_rope(unsigned short* __restrict__ P) {
    const int t = blockIdx.x * 256 + threadIdx.x;   // 8192*16 threads
    const int row = t >> 4;
    const int fe = (t & 15) * 2;                    // even freq index 0..30
    const float s = (float)(row & (SEQ - 1));
    const float C = 0.41524101186092034f;           // log2(10000)/32
    float sn0, cs0, sn1, cs1;
    sincosf(s * exp2f(-(float)fe * C), &sn0, &cs0);
    sincosf(s * exp2f(-(float)(fe + 1) * C), &sn1, &cs1);
    unsigned short* rowp = P + (size_t)row * NPROJ;
#pragma unroll
    for (int v = 0; v < 24; v++) {          // 12 heads x {q,k}
#pragma unroll
        for (int dd = 0; dd < 2; dd++) {    // d = fe and fe+32 share trig
            unsigned int* ap = (unsigned int*)(rowp + v * 64 + fe + dd * 32);
            unsigned int pk = *ap;
            float w0 = bf2f(pk & 0xFFFFu);
            float w1 = bf2f(pk >> 16);
            float o0 = w0 * cs0 - w1 * sn0;     // even: w*cos - w_odd*sin
            float o1 = w1 * cs1 + w0 * sn1;     // odd:  w*cos + w_even*sin
            *ap = (unsigned int)f2bf(o0) | ((unsigned int)f2bf(o1) << 16);
        }
    }
}

// ---- 4) logits[b,h,m,n] = (qw[b,m,h,:]·kw[b,n,h,:]*pad - (1-pad)*NEG - [n<m]*NEG)/8
__global__ __launch_bounds__(256) void k_attn(const unsigned short* __restrict__ P,
                                              const float* __restrict__ mask,
                                              float* __restrict__ out) {
    __shared__ unsigned short sQ[128][72];
    __shared__ unsigned short sK[128][72];
    const int tid = threadIdx.x;
    const int b = blockIdx.z, h = blockIdx.y;
    const int mt = blockIdx.x >> 2, nt = blockIdx.x & 3;
#pragma unroll
    for (int it = 0; it < 4; it++) {
        int c = tid + it * 256;
        int row = c >> 3, col = (c & 7) * 8;
        size_t gq = (size_t)(b * SEQ + mt * 128 + row) * NPROJ + h * 128 + col;
        *(int4*)&sQ[row][col] = *(const int4*)&P[gq];
        size_t gk = (size_t)(b * SEQ + nt * 128 + row) * NPROJ + h * 128 + 64 + col;
        *(int4*)&sK[row][col] = *(const int4*)&P[gk];
    }
    __syncthreads();
    const int lane = tid & 63, w = tid >> 6;
    const int q = lane >> 4, r = lane & 15;
    const int wm = w >> 1, wn = w & 1;
    f32x4 acc[4][4];
#pragma unroll
    for (int i = 0; i < 4; i++)
#pragma unroll
        for (int j = 0; j < 4; j++) acc[i][j] = (f32x4){0.f, 0.f, 0.f, 0.f};
#pragma unroll
    for (int kk = 0; kk < 64; kk += 32) {
        bf16x8 af[4], bfr[4];
#pragma unroll
        for (int t = 0; t < 4; t++)
            af[t] = *(const bf16x8*)&sQ[wm * 64 + t * 16 + r][kk + q * 8];
#pragma unroll
        for (int t = 0; t < 4; t++)
            bfr[t] = *(const bf16x8*)&sK[wn * 64 + t * 16 + r][kk + q * 8];
#pragma unroll
        for (int tm = 0; tm < 4; tm++)
#pragma unroll
            for (int tn = 0; tn < 4; tn++)
                acc[tm][tn] = __builtin_amdgcn_mfma_f32_16x16x32_bf16(
                    af[tm], bfr[tn], acc[tm][tn], 0, 0, 0);
    }
    // epilogue: pad/causal mask, scale 1/8
    float padv[4];
    int gns[4];
#pragma unroll
    for (int tn = 0; tn < 4; tn++) {
        gns[tn] = nt * 128 + wn * 64 + tn * 16 + r;
        padv[tn] = mask[b * SEQ + gns[tn]];
    }
#pragma unroll
    for (int tm = 0; tm < 4; tm++) {
        int gm = mt * 128 + wm * 64 + tm * 16 + q * 4;
#pragma unroll
        for (int i = 0; i < 4; i++) {
            int m = gm + i;
            float* orow = out + ((size_t)((b * NHEAD + h) * SEQ + m)) * SEQ;
#pragma unroll
            for (int tn = 0; tn < 4; tn++) {
                float v = acc[tm][tn][i];
                float pv = padv[tn];
                v = v * pv - (1.f - pv) * NEGV;
                if (gns[tn] < m) v -= NEGV;
                orow[gns[tn]] = v * 0.125f;
            }
        }
    }
}

extern "C" void kernel_launch(void* const* d_in, const int* in_sizes, int n_in,
                              void* d_out, int out_size, void* d_ws, size_t ws_size,
                              hipStream_t stream) {
    const float* x    = (const float*)d_in[0];   // (16,512,768)
    const float* mask = (const float*)d_in[1];   // (16,512)
    const float* W    = (const float*)d_in[2];   // (768,1536)
    const float* bias = (const float*)d_in[3];   // (1536,)
    float* out = (float*)d_out;                  // (16,12,512,512) fp32

    // ws layout: Wt bf16 [1536*768] (2.36 MB) | P bf16 [8192*1536] (25.2 MB)
    unsigned short* Wt = (unsigned short*)d_ws;
    unsigned short* P  = Wt + (size_t)NPROJ * DIN;

    k_wt  <<<dim3(NPROJ / 32, DIN / 32), dim3(32, 32), 0, stream>>>(W, Wt);
    k_gemm<<<dim3(NPROJ / 128, (NBATCH * SEQ) / 128), 256, 0, stream>>>(x, Wt, bias, P);
    k_rope<<<(NBATCH * SEQ * 16) / 256, 256, 0, stream>>>(P);
    k_attn<<<dim3(16, NHEAD, NBATCH), 256, 0, stream>>>(P, mask, out);
}

// Round 2
// 280.141 us; speedup vs baseline: 1.0143x; 1.0143x over previous
//
#include <hip/hip_runtime.h>
#include <stdint.h>

#define DIN   768
#define NPROJ 1536           // HID*OUT*2 = 64*12*2
#define SEQ   512
#define NHEAD 12
#define NBATCH 16
#define NEGV  1000000000000.0f

typedef short bf16x8 __attribute__((ext_vector_type(8)));
typedef float f32x4  __attribute__((ext_vector_type(4)));

__device__ __forceinline__ unsigned short f2bf(float f) {
    union { float f; unsigned int u; } v; v.f = f;
    return (unsigned short)((v.u + 0x7FFFu + ((v.u >> 16) & 1u)) >> 16);  // RTNE
}
__device__ __forceinline__ float bf2f(unsigned short u) {
    union { unsigned int u; float f; } v; v.u = ((unsigned int)u) << 16;
    return v.f;
}

// ---- 0) X fp32 -> bf16, fully coalesced ----
__global__ __launch_bounds__(256) void k_xcast(const float* __restrict__ X,
                                               unsigned short* __restrict__ Xb) {
    int i = (blockIdx.x * 256 + threadIdx.x) * 4;
    float4 v = *(const float4*)&X[i];
    short4 s;
    s.x = (short)f2bf(v.x); s.y = (short)f2bf(v.y);
    s.z = (short)f2bf(v.z); s.w = (short)f2bf(v.w);
    *(short4*)&Xb[i] = s;
}

// ---- 1) Wt[n][k] = bf16(W[k][n]), 64x64 tiles, int4 stores ----
__global__ __launch_bounds__(256) void k_wt(const float* __restrict__ W,
                                            unsigned short* __restrict__ Wt) {
    __shared__ unsigned short T[64][72];
    const int n0 = blockIdx.x * 64, k0 = blockIdx.y * 64;
    const int tid = threadIdx.x;
#pragma unroll
    for (int it = 0; it < 4; it++) {
        int c = tid + it * 256;
        int kl = c >> 4, nl = (c & 15) * 4;
        float4 v = *(const float4*)&W[(size_t)(k0 + kl) * NPROJ + n0 + nl];
        T[nl + 0][kl] = f2bf(v.x);
        T[nl + 1][kl] = f2bf(v.y);
        T[nl + 2][kl] = f2bf(v.z);
        T[nl + 3][kl] = f2bf(v.w);
    }
    __syncthreads();
#pragma unroll
    for (int it = 0; it < 2; it++) {
        int c = tid + it * 256;
        int nl = c >> 3, kb = (c & 7) * 8;
        *(int4*)&Wt[(size_t)(n0 + nl) * DIN + k0 + kb] = *(int4*)&T[nl][kb];
    }
}

// ---- 2) P[m][n] = bf16( Xb[m,:]·Wt[n,:] + b[n] ), 128x128 tile, bf16 MFMA ----
template <bool PRE>
__global__ __launch_bounds__(256) void k_gemm(const float* __restrict__ X,
                                              const unsigned short* __restrict__ Xb,
                                              const unsigned short* __restrict__ Wt,
                                              const float* __restrict__ bias,
                                              unsigned short* __restrict__ P) {
    __shared__ unsigned short smem[2 * 128 * 72];   // sA | sB, 72-stride (pad)
    unsigned short* sA = smem;
    unsigned short* sB = smem + 128 * 72;
    const int tid = threadIdx.x;
    const int m0 = blockIdx.y * 128, n0 = blockIdx.x * 128;
    const int lane = tid & 63, w = tid >> 6;
    const int q = lane >> 4, r = lane & 15;
    const int wm = w >> 1, wn = w & 1;
    f32x4 acc[4][4];
#pragma unroll
    for (int i = 0; i < 4; i++)
#pragma unroll
        for (int j = 0; j < 4; j++) acc[i][j] = (f32x4){0.f, 0.f, 0.f, 0.f};

    for (int k0 = 0; k0 < DIN; k0 += 64) {
        __syncthreads();
        if (PRE) {
#pragma unroll
            for (int it = 0; it < 4; it++) {
                int c = tid + it * 256;
                int row = c >> 3, col = (c & 7) * 8;
                *(int4*)&sA[row * 72 + col] =
                    *(const int4*)&Xb[(size_t)(m0 + row) * DIN + k0 + col];
            }
        } else {
#pragma unroll
            for (int it = 0; it < 8; it++) {
                int c = tid + it * 256;
                int row = c >> 4, col = (c & 15) * 4;
                float4 v = *(const float4*)&X[(size_t)(m0 + row) * DIN + k0 + col];
                short4 sv;
                sv.x = (short)f2bf(v.x); sv.y = (short)f2bf(v.y);
                sv.z = (short)f2bf(v.z); sv.w = (short)f2bf(v.w);
                *(short4*)&sA[row * 72 + col] = sv;
            }
        }
#pragma unroll
        for (int it = 0; it < 4; it++) {
            int c = tid + it * 256;
            int row = c >> 3, col = (c & 7) * 8;
            *(int4*)&sB[row * 72 + col] =
                *(const int4*)&Wt[(size_t)(n0 + row) * DIN + k0 + col];
        }
        __syncthreads();
#pragma unroll
        for (int kk = 0; kk < 64; kk += 32) {
            bf16x8 af[4], bfr[4];
#pragma unroll
            for (int t = 0; t < 4; t++)
                af[t] = *(const bf16x8*)&sA[(wm * 64 + t * 16 + r) * 72 + kk + q * 8];
#pragma unroll
            for (int t = 0; t < 4; t++)
                bfr[t] = *(const bf16x8*)&sB[(wn * 64 + t * 16 + r) * 72 + kk + q * 8];
#pragma unroll
            for (int tm = 0; tm < 4; tm++)
#pragma unroll
                for (int tn = 0; tn < 4; tn++)
                    acc[tm][tn] = __builtin_amdgcn_mfma_f32_16x16x32_bf16(
                        af[tm], bfr[tn], acc[tm][tn], 0, 0, 0);
        }
    }
    // epilogue: +bias -> bf16 -> LDS transpose -> int4 stores (256B row segments)
    float bb[4];
#pragma unroll
    for (int tn = 0; tn < 4; tn++) bb[tn] = bias[n0 + wn * 64 + tn * 16 + r];
    __syncthreads();                       // all waves done reading sA/sB
    unsigned short* sT = smem;             // 128 x 136 ushort = 34.8 KB
#pragma unroll
    for (int tm = 0; tm < 4; tm++) {
        int rowb = wm * 64 + tm * 16 + q * 4;
#pragma unroll
        for (int tn = 0; tn < 4; tn++) {
            int col = wn * 64 + tn * 16 + r;
#pragma unroll
            for (int i = 0; i < 4; i++)
                sT[(rowb + i) * 136 + col] = f2bf(acc[tm][tn][i] + bb[tn]);
        }
    }
    __syncthreads();
#pragma unroll
    for (int it = 0; it < 8; it++) {
        int c = tid + it * 256;
        int row = c >> 4, colb = (c & 15) * 8;
        *(int4*)&P[(size_t)(m0 + row) * NPROJ + n0 + colb] =
            *(int4*)&sT[row * 136 + colb];
    }
}

// ---- 3) RoPE in-place on P: one block per seq position s; LDS trig table;
//         fully-coalesced int4 RMW ----
__global__ __launch_bounds__(256) void k_rope(unsigned short* __restrict__ P) {
    const int s = blockIdx.x;
    const int tid = threadIdx.x;
    __shared__ float cs[32], sn[32];
    if (tid < 32) {
        const float C = 0.41524101186092034f;   // log2(10000)/32
        float a = (float)s * exp2f(-(float)tid * C);
        sincosf(a, &sn[tid], &cs[tid]);
    }
    __syncthreads();
#pragma unroll
    for (int it = 0; it < 12; it++) {
        int idx = tid + it * 256;              // 3072 int4-chunks
        int bb = idx / 192, c = idx % 192;     // 192 chunks per row
        unsigned short* p = P + (size_t)(bb * SEQ + s) * NPROJ + c * 8;
        union { int4 v; unsigned short u[8]; } pk;
        pk.v = *(const int4*)p;
        int d0 = (c & 7) * 8;                  // d of first element (even, 8-aligned)
        float wv[8];
#pragma unroll
        for (int j = 0; j < 8; j++) wv[j] = bf2f(pk.u[j]);
#pragma unroll
        for (int pr = 0; pr < 4; pr++) {
            int je = (d0 + 2 * pr) & 31;
            int jo = je + 1;
            float oe = wv[2 * pr] * cs[je] - wv[2 * pr + 1] * sn[je];
            float oo = wv[2 * pr + 1] * cs[jo] + wv[2 * pr] * sn[jo];
            pk.u[2 * pr]     = f2bf(oe);
            pk.u[2 * pr + 1] = f2bf(oo);
        }
        *(int4*)p = pk.v;
    }
}

// ---- 4) logits: per-head 128x128 QK^T tile + mask/causal/scale, float4 stores ----
__global__ __launch_bounds__(256) void k_attn(const unsigned short* __restrict__ P,
                                              const float* __restrict__ mask,
                                              float* __restrict__ out) {
    __shared__ unsigned short smem[2 * 128 * 72];   // sQ | sK; epilogue reuses as fp32
    unsigned short* sQ = smem;
    unsigned short* sK = smem + 128 * 72;
    const int tid = threadIdx.x;
    const int b = blockIdx.z, h = blockIdx.y;
    const int mt = blockIdx.x >> 2, nt = blockIdx.x & 3;
#pragma unroll
    for (int it = 0; it < 4; it++) {
        int c = tid + it * 256;
        int row = c >> 3, col = (c & 7) * 8;
        size_t gq = (size_t)(b * SEQ + mt * 128 + row) * NPROJ + h * 128 + col;
        *(int4*)&sQ[row * 72 + col] = *(const int4*)&P[gq];
        size_t gk = (size_t)(b * SEQ + nt * 128 + row) * NPROJ + h * 128 + 64 + col;
        *(int4*)&sK[row * 72 + col] = *(const int4*)&P[gk];
    }
    __syncthreads();
    const int lane = tid & 63, w = tid >> 6;
    const int q = lane >> 4, r = lane & 15;
    const int wm = w >> 1, wn = w & 1;
    f32x4 acc[4][4];
#pragma unroll
    for (int i = 0; i < 4; i++)
#pragma unroll
        for (int j = 0; j < 4; j++) acc[i][j] = (f32x4){0.f, 0.f, 0.f, 0.f};
#pragma unroll
    for (int kk = 0; kk < 64; kk += 32) {
        bf16x8 af[4], bfr[4];
#pragma unroll
        for (int t = 0; t < 4; t++)
            af[t] = *(const bf16x8*)&sQ[(wm * 64 + t * 16 + r) * 72 + kk + q * 8];
#pragma unroll
        for (int t = 0; t < 4; t++)
            bfr[t] = *(const bf16x8*)&sK[(wn * 64 + t * 16 + r) * 72 + kk + q * 8];
#pragma unroll
        for (int tm = 0; tm < 4; tm++)
#pragma unroll
            for (int tn = 0; tn < 4; tn++)
                acc[tm][tn] = __builtin_amdgcn_mfma_f32_16x16x32_bf16(
                    af[tm], bfr[tn], acc[tm][tn], 0, 0, 0);
    }
    // epilogue: per-tm stripes through LDS -> float4 stores (512B row segments)
    float* sbuf = (float*)smem;            // 32 x 132 fp32 = 16.9 KB
    const int rowb = wm * 16 + q * 4;
#pragma unroll
    for (int tm = 0; tm < 4; tm++) {
        __syncthreads();
#pragma unroll
        for (int tn = 0; tn < 4; tn++) {
            int col = wn * 64 + tn * 16 + r;
#pragma unroll
            for (int i = 0; i < 4; i++)
                sbuf[(rowb + i) * 132 + col] = acc[tm][tn][i];
        }
        __syncthreads();
#pragma unroll
        for (int it = 0; it < 4; it++) {
            int c = tid + it * 256;        // 1024 float4s = 32 rows x 128 cols
            int rl = c >> 5, cb = (c & 31) * 4;
            float4 v = *(float4*)&sbuf[rl * 132 + cb];
            int m = mt * 128 + (rl >> 4) * 64 + tm * 16 + (rl & 15);
            int n = nt * 128 + cb;
            float4 mk = *(const float4*)&mask[b * SEQ + n];
            float4 o;
            o.x = (v.x * mk.x - (1.f - mk.x) * NEGV - ((n + 0) < m ? NEGV : 0.f)) * 0.125f;
            o.y = (v.y * mk.y - (1.f - mk.y) * NEGV - ((n + 1) < m ? NEGV : 0.f)) * 0.125f;
            o.z = (v.z * mk.z - (1.f - mk.z) * NEGV - ((n + 2) < m ? NEGV : 0.f)) * 0.125f;
            o.w = (v.w * mk.w - (1.f - mk.w) * NEGV - ((n + 3) < m ? NEGV : 0.f)) * 0.125f;
            *(float4*)&out[((size_t)((b * NHEAD + h) * SEQ + m)) * SEQ + n] = o;
        }
    }
}

extern "C" void kernel_launch(void* const* d_in, const int* in_sizes, int n_in,
                              void* d_out, int out_size, void* d_ws, size_t ws_size,
                              hipStream_t stream) {
    const float* x    = (const float*)d_in[0];   // (16,512,768)
    const float* mask = (const float*)d_in[1];   // (16,512)
    const float* W    = (const float*)d_in[2];   // (768,1536)
    const float* bias = (const float*)d_in[3];   // (1536,)
    float* out = (float*)d_out;                  // (16,12,512,512) fp32

    const size_t wtN = (size_t)NPROJ * DIN;          // 1.18 M
    const size_t pN  = (size_t)NBATCH * SEQ * NPROJ; // 12.58 M
    const size_t xN  = (size_t)NBATCH * SEQ * DIN;   // 6.29 M
    unsigned short* Wt = (unsigned short*)d_ws;
    unsigned short* P  = Wt + wtN;
    unsigned short* Xb = P + pN;
    const bool pre = ws_size >= (wtN + pN + xN) * sizeof(unsigned short);

    k_wt<<<dim3(NPROJ / 64, DIN / 64), 256, 0, stream>>>(W, Wt);
    if (pre) {
        k_xcast<<<(int)(xN / (256 * 4)), 256, 0, stream>>>(x, Xb);
        k_gemm<true><<<dim3(NPROJ / 128, (NBATCH * SEQ) / 128), 256, 0, stream>>>(
            x, Xb, Wt, bias, P);
    } else {
        k_gemm<false><<<dim3(NPROJ / 128, (NBATCH * SEQ) / 128), 256, 0, stream>>>(
            x, nullptr, Wt, bias, P);
    }
    k_rope<<<SEQ, 256, 0, stream>>>(P);
    k_attn<<<dim3(16, NHEAD, NBATCH), 256, 0, stream>>>(P, mask, out);
}

// Round 4
// 276.962 us; speedup vs baseline: 1.0260x; 1.0115x over previous
//
#include <hip/hip_runtime.h>
#include <stdint.h>

#define DIN   768
#define NPROJ 1536           // HID*OUT*2 = 64*12*2
#define SEQ   512
#define NHEAD 12
#define NBATCH 16
#define NEGV  1000000000000.0f

typedef short bf16x8 __attribute__((ext_vector_type(8)));
typedef float f32x4  __attribute__((ext_vector_type(4)));

__device__ __forceinline__ unsigned short f2bf(float f) {
    union { float f; unsigned int u; } v; v.f = f;
    return (unsigned short)((v.u + 0x7FFFu + ((v.u >> 16) & 1u)) >> 16);  // RTNE
}
__device__ __forceinline__ float bf2f(unsigned short u) {
    union { unsigned int u; float f; } v; v.u = ((unsigned int)u) << 16;
    return v.f;
}

// ---- 0a) trig table: trig[s][j] = (cos,sin)(s * 10000^(-j/32)), 512x32 float2 ----
__global__ __launch_bounds__(256) void k_trig(float* __restrict__ trig) {
    int gi = blockIdx.x * 256 + threadIdx.x;     // 16384 = 512*32
    int ss = gi >> 5, j = gi & 31;
    const float C = 0.41524101186092034f;        // log2(10000)/32
    float cs, sn;
    sincosf((float)ss * exp2f(-(float)j * C), &sn, &cs);
    trig[2 * gi]     = cs;
    trig[2 * gi + 1] = sn;
}

// ---- 0b) X fp32 -> bf16, fully coalesced ----
__global__ __launch_bounds__(256) void k_xcast(const float* __restrict__ X,
                                               unsigned short* __restrict__ Xb) {
    int i = (blockIdx.x * 256 + threadIdx.x) * 4;
    float4 v = *(const float4*)&X[i];
    short4 s;
    s.x = (short)f2bf(v.x); s.y = (short)f2bf(v.y);
    s.z = (short)f2bf(v.z); s.w = (short)f2bf(v.w);
    *(short4*)&Xb[i] = s;
}

// ---- 1) Wt[n][k] = bf16(W[k][n]), 64x64 tiles, int4 stores ----
__global__ __launch_bounds__(256) void k_wt(const float* __restrict__ W,
                                            unsigned short* __restrict__ Wt) {
    __shared__ unsigned short T[64][72];
    const int n0 = blockIdx.x * 64, k0 = blockIdx.y * 64;
    const int tid = threadIdx.x;
#pragma unroll
    for (int it = 0; it < 4; it++) {
        int c = tid + it * 256;
        int kl = c >> 4, nl = (c & 15) * 4;
        float4 v = *(const float4*)&W[(size_t)(k0 + kl) * NPROJ + n0 + nl];
        T[nl + 0][kl] = f2bf(v.x);
        T[nl + 1][kl] = f2bf(v.y);
        T[nl + 2][kl] = f2bf(v.z);
        T[nl + 3][kl] = f2bf(v.w);
    }
    __syncthreads();
#pragma unroll
    for (int it = 0; it < 2; it++) {
        int c = tid + it * 256;
        int nl = c >> 3, kb = (c & 7) * 8;
        *(int4*)&Wt[(size_t)(n0 + nl) * DIN + k0 + kb] = *(int4*)&T[nl][kb];
    }
}

// ---- 2) P = rope( bf16(X@W + b) ), 128x128 tile MFMA, RoPE fused in store phase ----
template <bool PRE>
__global__ __launch_bounds__(256) void k_gemm(const float* __restrict__ X,
                                              const unsigned short* __restrict__ Xb,
                                              const unsigned short* __restrict__ Wt,
                                              const float* __restrict__ bias,
                                              const float* __restrict__ trig,
                                              unsigned short* __restrict__ P) {
    __shared__ unsigned short smem[2 * 128 * 72];   // sA | sB (72-stride pad)
    unsigned short* sA = smem;
    unsigned short* sB = smem + 128 * 72;
    const int tid = threadIdx.x;
    const int m0 = blockIdx.y * 128, n0 = blockIdx.x * 128;
    const int lane = tid & 63, w = tid >> 6;
    const int q = lane >> 4, r = lane & 15;
    const int wm = w >> 1, wn = w & 1;
    f32x4 acc[4][4];
#pragma unroll
    for (int i = 0; i < 4; i++)
#pragma unroll
        for (int j = 0; j < 4; j++) acc[i][j] = (f32x4){0.f, 0.f, 0.f, 0.f};

    for (int k0 = 0; k0 < DIN; k0 += 64) {
        __syncthreads();
        if (PRE) {
#pragma unroll
            for (int it = 0; it < 4; it++) {
                int c = tid + it * 256;
                int row = c >> 3, col = (c & 7) * 8;
                *(int4*)&sA[row * 72 + col] =
                    *(const int4*)&Xb[(size_t)(m0 + row) * DIN + k0 + col];
            }
        } else {
#pragma unroll
            for (int it = 0; it < 8; it++) {
                int c = tid + it * 256;
                int row = c >> 4, col = (c & 15) * 4;
                float4 v = *(const float4*)&X[(size_t)(m0 + row) * DIN + k0 + col];
                short4 sv;
                sv.x = (short)f2bf(v.x); sv.y = (short)f2bf(v.y);
                sv.z = (short)f2bf(v.z); sv.w = (short)f2bf(v.w);
                *(short4*)&sA[row * 72 + col] = sv;
            }
        }
#pragma unroll
        for (int it = 0; it < 4; it++) {
            int c = tid + it * 256;
            int row = c >> 3, col = (c & 7) * 8;
            *(int4*)&sB[row * 72 + col] =
                *(const int4*)&Wt[(size_t)(n0 + row) * DIN + k0 + col];
        }
        __syncthreads();
#pragma unroll
        for (int kk = 0; kk < 64; kk += 32) {
            bf16x8 af[4], bfr[4];
#pragma unroll
            for (int t = 0; t < 4; t++)
                af[t] = *(const bf16x8*)&sA[(wm * 64 + t * 16 + r) * 72 + kk + q * 8];
#pragma unroll
            for (int t = 0; t < 4; t++)
                bfr[t] = *(const bf16x8*)&sB[(wn * 64 + t * 16 + r) * 72 + kk + q * 8];
#pragma unroll
            for (int tm = 0; tm < 4; tm++)
#pragma unroll
                for (int tn = 0; tn < 4; tn++)
                    acc[tm][tn] = __builtin_amdgcn_mfma_f32_16x16x32_bf16(
                        af[tm], bfr[tn], acc[tm][tn], 0, 0, 0);
        }
    }
    // epilogue: +bias -> bf16 -> LDS transpose -> RoPE -> int4 stores
    float bb[4];
#pragma unroll
    for (int tn = 0; tn < 4; tn++) bb[tn] = bias[n0 + wn * 64 + tn * 16 + r];
    __syncthreads();
    unsigned short* sT = smem;             // 128 x 136 ushort
#pragma unroll
    for (int tm = 0; tm < 4; tm++) {
        int rowb = wm * 64 + tm * 16 + q * 4;
#pragma unroll
        for (int tn = 0; tn < 4; tn++) {
            int col = wn * 64 + tn * 16 + r;
#pragma unroll
            for (int i = 0; i < 4; i++)
                sT[(rowb + i) * 136 + col] = f2bf(acc[tm][tn][i] + bb[tn]);
        }
    }
    __syncthreads();
#pragma unroll
    for (int it = 0; it < 8; it++) {
        int c = tid + it * 256;
        int row = c >> 4, colb = (c & 15) * 8;
        int m = m0 + row;
        int s = m & (SEQ - 1);
        int base = colb & 31;              // trig j of first channel
        union { int4 v; unsigned short u[8]; } pk;
        pk.v = *(int4*)&sT[row * 136 + colb];
        float wv[8];
#pragma unroll
        for (int j = 0; j < 8; j++) wv[j] = bf2f(pk.u[j]);
        const float* tp = &trig[2 * (s * 32 + base)];
#pragma unroll
        for (int p = 0; p < 4; p++) {
            float4 tt = *(const float4*)&tp[4 * p];  // (cs_e, sn_e, cs_o, sn_o)
            float oe = wv[2 * p] * tt.x - wv[2 * p + 1] * tt.y;
            float oo = wv[2 * p + 1] * tt.z + wv[2 * p] * tt.w;
            pk.u[2 * p]     = f2bf(oe);
            pk.u[2 * p + 1] = f2bf(oo);
        }
        *(int4*)&P[(size_t)m * NPROJ + n0 + colb] = pk.v;
    }
}

// ---- 3) logits: 128x128 QK^T tile + mask/causal/scale; causal-skip; NT stores ----
__global__ __launch_bounds__(256) void k_attn(const unsigned short* __restrict__ P,
                                              const float* __restrict__ mask,
                                              float* __restrict__ out) {
    __shared__ unsigned short smem[2 * 128 * 72];   // sQ | sK; epilogue reuses as fp32
    unsigned short* sQ = smem;
    unsigned short* sK = smem + 128 * 72;
    const int tid = threadIdx.x;
    const int b = blockIdx.z, h = blockIdx.y;
    const int mt = blockIdx.x >> 2, nt = blockIdx.x & 3;
    const size_t obase = ((size_t)((b * NHEAD + h) * SEQ)) * SEQ;

    if (nt < mt) {
        // fully causal-masked tile: out = (-(1-pad)*NEG - NEG)/8 ; |qk/8| << threshold
#pragma unroll
        for (int it = 0; it < 16; it++) {
            int c = tid + it * 256;            // 4096 f32x4 = 128 rows x 32 chunks
            int rl = c >> 5, cb = (c & 31) * 4;
            int m = mt * 128 + rl, n = nt * 128 + cb;
            f32x4 mk = *(const f32x4*)&mask[b * SEQ + n];
            f32x4 o;
#pragma unroll
            for (int j = 0; j < 4; j++)
                o[j] = (-(1.f - mk[j]) * NEGV - NEGV) * 0.125f;
            __builtin_nontemporal_store(o, (f32x4*)&out[obase + (size_t)m * SEQ + n]);
        }
        return;
    }

#pragma unroll
    for (int it = 0; it < 4; it++) {
        int c = tid + it * 256;
        int row = c >> 3, col = (c & 7) * 8;
        size_t gq = (size_t)(b * SEQ + mt * 128 + row) * NPROJ + h * 128 + col;
        *(int4*)&sQ[row * 72 + col] = *(const int4*)&P[gq];
        size_t gk = (size_t)(b * SEQ + nt * 128 + row) * NPROJ + h * 128 + 64 + col;
        *(int4*)&sK[row * 72 + col] = *(const int4*)&P[gk];
    }
    __syncthreads();
    const int lane = tid & 63, w = tid >> 6;
    const int q = lane >> 4, r = lane & 15;
    const int wm = w >> 1, wn = w & 1;
    f32x4 acc[4][4];
#pragma unroll
    for (int i = 0; i < 4; i++)
#pragma unroll
        for (int j = 0; j < 4; j++) acc[i][j] = (f32x4){0.f, 0.f, 0.f, 0.f};
#pragma unroll
    for (int kk = 0; kk < 64; kk += 32) {
        bf16x8 af[4], bfr[4];
#pragma unroll
        for (int t = 0; t < 4; t++)
            af[t] = *(const bf16x8*)&sQ[(wm * 64 + t * 16 + r) * 72 + kk + q * 8];
#pragma unroll
        for (int t = 0; t < 4; t++)
            bfr[t] = *(const bf16x8*)&sK[(wn * 64 + t * 16 + r) * 72 + kk + q * 8];
#pragma unroll
        for (int tm = 0; tm < 4; tm++)
#pragma unroll
            for (int tn = 0; tn < 4; tn++)
                acc[tm][tn] = __builtin_amdgcn_mfma_f32_16x16x32_bf16(
                    af[tm], bfr[tn], acc[tm][tn], 0, 0, 0);
    }
    // epilogue: per-tm stripes through LDS -> NT f32x4 stores
    float* sbuf = (float*)smem;            // 32 x 132 fp32
    const int rowb = wm * 16 + q * 4;
#pragma unroll
    for (int tm = 0; tm < 4; tm++) {
        __syncthreads();
#pragma unroll
        for (int tn = 0; tn < 4; tn++) {
            int col = wn * 64 + tn * 16 + r;
#pragma unroll
            for (int i = 0; i < 4; i++)
                sbuf[(rowb + i) * 132 + col] = acc[tm][tn][i];
        }
        __syncthreads();
#pragma unroll
        for (int it = 0; it < 4; it++) {
            int c = tid + it * 256;        // 1024 f32x4 = 32 rows x 128 cols
            int rl = c >> 5, cb = (c & 31) * 4;
            f32x4 v = *(f32x4*)&sbuf[rl * 132 + cb];
            int m = mt * 128 + (rl >> 4) * 64 + tm * 16 + (rl & 15);
            int n = nt * 128 + cb;
            f32x4 mk = *(const f32x4*)&mask[b * SEQ + n];
            f32x4 o;
#pragma unroll
            for (int j = 0; j < 4; j++)
                o[j] = (v[j] * mk[j] - (1.f - mk[j]) * NEGV
                        - ((n + j) < m ? NEGV : 0.f)) * 0.125f;
            __builtin_nontemporal_store(o, (f32x4*)&out[obase + (size_t)m * SEQ + n]);
        }
    }
}

extern "C" void kernel_launch(void* const* d_in, const int* in_sizes, int n_in,
                              void* d_out, int out_size, void* d_ws, size_t ws_size,
                              hipStream_t stream) {
    const float* x    = (const float*)d_in[0];   // (16,512,768)
    const float* mask = (const float*)d_in[1];   // (16,512)
    const float* W    = (const float*)d_in[2];   // (768,1536)
    const float* bias = (const float*)d_in[3];   // (1536,)
    float* out = (float*)d_out;                  // (16,12,512,512) fp32

    const size_t wtN = (size_t)NPROJ * DIN;          // 1.18 M ush
    const size_t pN  = (size_t)NBATCH * SEQ * NPROJ; // 12.58 M ush
    const size_t xN  = (size_t)NBATCH * SEQ * DIN;   // 6.29 M ush
    const size_t trigN = (size_t)SEQ * 32 * 2;       // 32 K floats
    unsigned short* Wt = (unsigned short*)d_ws;
    unsigned short* P  = Wt + wtN;
    float* trig        = (float*)(P + pN);
    unsigned short* Xb = (unsigned short*)(trig + trigN);
    const bool pre = ws_size >= (wtN + pN) * sizeof(unsigned short)
                               + trigN * sizeof(float)
                               + xN * sizeof(unsigned short);

    k_trig<<<SEQ * 32 / 256, 256, 0, stream>>>(trig);
    k_wt<<<dim3(NPROJ / 64, DIN / 64), 256, 0, stream>>>(W, Wt);
    if (pre) {
        k_xcast<<<(int)(xN / (256 * 4)), 256, 0, stream>>>(x, Xb);
        k_gemm<true><<<dim3(NPROJ / 128, (NBATCH * SEQ) / 128), 256, 0, stream>>>(
            x, Xb, Wt, bias, trig, P);
    } else {
        k_gemm<false><<<dim3(NPROJ / 128, (NBATCH * SEQ) / 128), 256, 0, stream>>>(
            x, nullptr, Wt, bias, trig, P);
    }
    k_attn<<<dim3(16, NHEAD, NBATCH), 256, 0, stream>>>(P, mask, out);
}

// Round 5
// 273.845 us; speedup vs baseline: 1.0376x; 1.0114x over previous
//
#include <hip/hip_runtime.h>
#include <stdint.h>

#define DIN   768
#define NPROJ 1536           // HID*OUT*2 = 64*12*2
#define SEQ   512
#define NHEAD 12
#define NBATCH 16
#define NEGV  1000000000000.0f

typedef short bf16x8 __attribute__((ext_vector_type(8)));
typedef float f32x4  __attribute__((ext_vector_type(4)));
typedef unsigned short u16x8 __attribute__((ext_vector_type(8)));

__device__ __forceinline__ unsigned short f2bf(float f) {
    union { float f; unsigned int u; } v; v.f = f;
    return (unsigned short)((v.u + 0x7FFFu + ((v.u >> 16) & 1u)) >> 16);  // RTNE
}
__device__ __forceinline__ float bf2f(unsigned short u) {
    union { unsigned int u; float f; } v; v.u = ((unsigned int)u) << 16;
    return v.f;
}

// async global->LDS, 16B/lane (global_load_lds_dwordx4). LDS dest is
// wave-uniform base + lane*16 (m104/m108) — layout must be lane-ordered.
__device__ __forceinline__ void gl_lds16(const unsigned short* g, unsigned short* l) {
    __builtin_amdgcn_global_load_lds(
        (const __attribute__((address_space(1))) unsigned int*)(uintptr_t)g,
        (__attribute__((address_space(3))) unsigned int*)(uintptr_t)l,
        16, 0, 0);
}

// Stage a 128x64-bf16 tile (16 KB) into lds[128*64], XOR-swizzled on the
// GLOBAL side: LDS[row][c16] holds global col16 (c16 ^ (row&7)). Fragment
// reads at col16 cg then use LDS col (cg ^ (row&7)) -> 8 bank-groups across
// 16 lanes = free 2-way conflicts, no padding needed (gl_lds requires none).
__device__ __forceinline__ void stage128x64(const unsigned short* __restrict__ g,
                                            int gstride, unsigned short* lds,
                                            int w, int lane) {
#pragma unroll
    for (int t = 0; t < 4; t++) {
        int lr = w * 32 + t * 8 + (lane >> 3);
        int c16 = (lane & 7) ^ (lr & 7);
        gl_lds16(g + (size_t)lr * gstride + c16 * 8,
                 lds + (w * 32 + t * 8) * 64);
    }
}
__device__ __forceinline__ int swz(int row, int cg) {   // LDS short index
    return row * 64 + ((cg ^ (row & 7)) << 3);
}

// ---- 0) prep: Wt transpose+cast | trig table | X->bf16, one launch ----
__global__ __launch_bounds__(256) void k_prep(const float* __restrict__ X,
                                              unsigned short* __restrict__ Xb,
                                              const float* __restrict__ W,
                                              unsigned short* __restrict__ Wt,
                                              float* __restrict__ trig) {
    __shared__ unsigned short T[64][72];
    const int bid = blockIdx.x, tid = threadIdx.x;
    if (bid < 288) {                       // Wt[n][k] = bf16(W[k][n])
        int n0 = (bid % 24) * 64, k0 = (bid / 24) * 64;
#pragma unroll
        for (int it = 0; it < 4; it++) {
            int c = tid + it * 256;
            int kl = c >> 4, nl = (c & 15) * 4;
            float4 v = *(const float4*)&W[(size_t)(k0 + kl) * NPROJ + n0 + nl];
            T[nl + 0][kl] = f2bf(v.x);
            T[nl + 1][kl] = f2bf(v.y);
            T[nl + 2][kl] = f2bf(v.z);
            T[nl + 3][kl] = f2bf(v.w);
        }
        __syncthreads();
#pragma unroll
        for (int it = 0; it < 2; it++) {
            int c = tid + it * 256;
            int nl = c >> 3, kb = (c & 7) * 8;
            *(int4*)&Wt[(size_t)(n0 + nl) * DIN + k0 + kb] = *(int4*)&T[nl][kb];
        }
        return;
    }
    if (bid < 352) {                       // trig[s][j] = (cos,sin)(s*10000^(-j/32))
        int gi = (bid - 288) * 256 + tid;
        int ss = gi >> 5, j = gi & 31;
        const float C = 0.41524101186092034f;   // log2(10000)/32
        float cs, sn;
        sincosf((float)ss * exp2f(-(float)j * C), &sn, &cs);
        trig[2 * gi]     = cs;
        trig[2 * gi + 1] = sn;
        return;
    }
    int i = ((bid - 352) * 256 + tid) * 4; // X -> bf16
    float4 v = *(const float4*)&X[i];
    short4 s;
    s.x = (short)f2bf(v.x); s.y = (short)f2bf(v.y);
    s.z = (short)f2bf(v.z); s.w = (short)f2bf(v.w);
    *(short4*)&Xb[i] = s;
}

// ---- 1) P = rope( bf16(X@W + b) ), 128x128 tile MFMA, gl_lds staging ----
template <bool PRE>
__global__ __launch_bounds__(256) void k_gemm(const float* __restrict__ X,
                                              const unsigned short* __restrict__ Xb,
                                              const unsigned short* __restrict__ Wt,
                                              const float* __restrict__ bias,
                                              const float* __restrict__ trig,
                                              unsigned short* __restrict__ P) {
    __shared__ unsigned short smem[17408];  // sA(8192)|sB(8192); epilogue sT(128x136)
    unsigned short* sA = smem;
    unsigned short* sB = smem + 8192;
    const int tid = threadIdx.x;
    const int m0 = blockIdx.y * 128, n0 = blockIdx.x * 128;
    const int lane = tid & 63, w = tid >> 6;
    const int q = lane >> 4, r = lane & 15;
    const int wm = w >> 1, wn = w & 1;
    f32x4 acc[4][4];
#pragma unroll
    for (int i = 0; i < 4; i++)
#pragma unroll
        for (int j = 0; j < 4; j++) acc[i][j] = (f32x4){0.f, 0.f, 0.f, 0.f};

    const unsigned short* Ag = Xb + (size_t)m0 * DIN;
    const unsigned short* Bg = Wt + (size_t)n0 * DIN;

    for (int k0 = 0; k0 < DIN; k0 += 64) {
        __syncthreads();
        if (PRE) {
            stage128x64(Ag + k0, DIN, sA, w, lane);
        } else {
#pragma unroll
            for (int it = 0; it < 4; it++) {
                int c = tid + it * 256;
                int row = c >> 3, c16 = c & 7;
                const float* xp = &X[(size_t)(m0 + row) * DIN + k0 + c16 * 8];
                float4 v0 = *(const float4*)xp;
                float4 v1 = *(const float4*)(xp + 4);
                u16x8 sv;
                sv[0] = f2bf(v0.x); sv[1] = f2bf(v0.y);
                sv[2] = f2bf(v0.z); sv[3] = f2bf(v0.w);
                sv[4] = f2bf(v1.x); sv[5] = f2bf(v1.y);
                sv[6] = f2bf(v1.z); sv[7] = f2bf(v1.w);
                *(u16x8*)&sA[swz(row, c16)] = sv;
            }
        }
        stage128x64(Bg + k0, DIN, sB, w, lane);
        __syncthreads();
#pragma unroll
        for (int kk = 0; kk < 64; kk += 32) {
            const int cg = (kk >> 3) + q;
            bf16x8 af[4], bfr[4];
#pragma unroll
            for (int t = 0; t < 4; t++)
                af[t] = *(const bf16x8*)&sA[swz(wm * 64 + t * 16 + r, cg)];
#pragma unroll
            for (int t = 0; t < 4; t++)
                bfr[t] = *(const bf16x8*)&sB[swz(wn * 64 + t * 16 + r, cg)];
#pragma unroll
            for (int tm = 0; tm < 4; tm++)
#pragma unroll
                for (int tn = 0; tn < 4; tn++)
                    acc[tm][tn] = __builtin_amdgcn_mfma_f32_16x16x32_bf16(
                        af[tm], bfr[tn], acc[tm][tn], 0, 0, 0);
        }
    }
    // epilogue: +bias -> bf16 -> LDS transpose -> RoPE -> int4 stores
    float bb[4];
#pragma unroll
    for (int tn = 0; tn < 4; tn++) bb[tn] = bias[n0 + wn * 64 + tn * 16 + r];
    __syncthreads();
    unsigned short* sT = smem;             // 128 x 136 ushort
#pragma unroll
    for (int tm = 0; tm < 4; tm++) {
        int rowb = wm * 64 + tm * 16 + q * 4;
#pragma unroll
        for (int tn = 0; tn < 4; tn++) {
            int col = wn * 64 + tn * 16 + r;
#pragma unroll
            for (int i = 0; i < 4; i++)
                sT[(rowb + i) * 136 + col] = f2bf(acc[tm][tn][i] + bb[tn]);
        }
    }
    __syncthreads();
#pragma unroll
    for (int it = 0; it < 8; it++) {
        int c = tid + it * 256;
        int row = c >> 4, colb = (c & 15) * 8;
        int m = m0 + row;
        int s = m & (SEQ - 1);
        int base = colb & 31;              // trig j of first channel
        union { int4 v; unsigned short u[8]; } pk;
        pk.v = *(int4*)&sT[row * 136 + colb];
        float wv[8];
#pragma unroll
        for (int j = 0; j < 8; j++) wv[j] = bf2f(pk.u[j]);
        const float* tp = &trig[2 * (s * 32 + base)];
#pragma unroll
        for (int p = 0; p < 4; p++) {
            float4 tt = *(const float4*)&tp[4 * p];  // (cs_e, sn_e, cs_o, sn_o)
            float oe = wv[2 * p] * tt.x - wv[2 * p + 1] * tt.y;
            float oo = wv[2 * p + 1] * tt.z + wv[2 * p] * tt.w;
            pk.u[2 * p]     = f2bf(oe);
            pk.u[2 * p + 1] = f2bf(oo);
        }
        *(int4*)&P[(size_t)m * NPROJ + n0 + colb] = pk.v;
    }
}

// ---- 2) logits: row-strip blocks (mt,h,b); Q staged once; causal-skip ----
__global__ __launch_bounds__(256) void k_attn(const unsigned short* __restrict__ P,
                                              const float* __restrict__ mask,
                                              float* __restrict__ out) {
    __shared__ unsigned short sQ[8192], sK[8192];
    __shared__ float sbuf[32 * 132];
    const int tid = threadIdx.x;
    const int b = blockIdx.z, h = blockIdx.y, mt = blockIdx.x;
    const int lane = tid & 63, w = tid >> 6;
    const int q = lane >> 4, r = lane & 15;
    const int wm = w >> 1, wn = w & 1;
    const size_t obase = ((size_t)((b * NHEAD + h) * SEQ)) * SEQ;

    const unsigned short* Qg = P + (size_t)(b * SEQ + mt * 128) * NPROJ + h * 128;
    stage128x64(Qg, NPROJ, sQ, w, lane);

    bf16x8 aq[2][4];
    bool qload = false;
    for (int nt = 0; nt < 4; nt++) {
        const int ncol0 = nt * 128;
        if (nt < mt) {
            // fully causal-masked tile: out = (-(1-pad)*NEG - NEG)/8
#pragma unroll
            for (int it = 0; it < 16; it++) {
                int c = tid + it * 256;
                int rl = c >> 5, cb = (c & 31) * 4;
                int m = mt * 128 + rl, n = ncol0 + cb;
                f32x4 mk = *(const f32x4*)&mask[b * SEQ + n];
                f32x4 o;
#pragma unroll
                for (int j = 0; j < 4; j++)
                    o[j] = (-(1.f - mk[j]) * NEGV - NEGV) * 0.125f;
                __builtin_nontemporal_store(o, (f32x4*)&out[obase + (size_t)m * SEQ + n]);
            }
            continue;
        }
        __syncthreads();   // prior tile's sK reads done; also drains Q staging
        const unsigned short* Kg =
            P + (size_t)(b * SEQ + nt * 128) * NPROJ + h * 128 + 64;
        stage128x64(Kg, NPROJ, sK, w, lane);
        __syncthreads();
        if (!qload) {
            qload = true;
#pragma unroll
            for (int x2 = 0; x2 < 2; x2++) {
                int cg = x2 * 4 + q;
#pragma unroll
                for (int t = 0; t < 4; t++)
                    aq[x2][t] = *(const bf16x8*)&sQ[swz(wm * 64 + t * 16 + r, cg)];
            }
        }
        f32x4 acc[4][4];
#pragma unroll
        for (int i = 0; i < 4; i++)
#pragma unroll
            for (int j = 0; j < 4; j++) acc[i][j] = (f32x4){0.f, 0.f, 0.f, 0.f};
#pragma unroll
        for (int x2 = 0; x2 < 2; x2++) {
            int cg = x2 * 4 + q;
            bf16x8 bfr[4];
#pragma unroll
            for (int t = 0; t < 4; t++)
                bfr[t] = *(const bf16x8*)&sK[swz(wn * 64 + t * 16 + r, cg)];
#pragma unroll
            for (int tm = 0; tm < 4; tm++)
#pragma unroll
                for (int tn = 0; tn < 4; tn++)
                    acc[tm][tn] = __builtin_amdgcn_mfma_f32_16x16x32_bf16(
                        aq[x2][tm], bfr[tn], acc[tm][tn], 0, 0, 0);
        }
        // epilogue: 32-row stripes through LDS -> NT f32x4 stores
        const int rowb = wm * 16 + q * 4;
#pragma unroll
        for (int tm = 0; tm < 4; tm++) {
            __syncthreads();
#pragma unroll
            for (int tn = 0; tn < 4; tn++) {
                int col = wn * 64 + tn * 16 + r;
#pragma unroll
                for (int i = 0; i < 4; i++)
                    sbuf[(rowb + i) * 132 + col] = acc[tm][tn][i];
            }
            __syncthreads();
#pragma unroll
            for (int it = 0; it < 4; it++) {
                int c = tid + it * 256;
                int rl = c >> 5, cb = (c & 31) * 4;
                f32x4 v = *(f32x4*)&sbuf[rl * 132 + cb];
                int m = mt * 128 + (rl >> 4) * 64 + tm * 16 + (rl & 15);
                int n = ncol0 + cb;
                f32x4 mk = *(const f32x4*)&mask[b * SEQ + n];
                f32x4 o;
#pragma unroll
                for (int j = 0; j < 4; j++)
                    o[j] = (v[j] * mk[j] - (1.f - mk[j]) * NEGV
                            - ((n + j) < m ? NEGV : 0.f)) * 0.125f;
                __builtin_nontemporal_store(o, (f32x4*)&out[obase + (size_t)m * SEQ + n]);
            }
        }
    }
}

extern "C" void kernel_launch(void* const* d_in, const int* in_sizes, int n_in,
                              void* d_out, int out_size, void* d_ws, size_t ws_size,
                              hipStream_t stream) {
    const float* x    = (const float*)d_in[0];   // (16,512,768)
    const float* mask = (const float*)d_in[1];   // (16,512)
    const float* W    = (const float*)d_in[2];   // (768,1536)
    const float* bias = (const float*)d_in[3];   // (1536,)
    float* out = (float*)d_out;                  // (16,12,512,512) fp32

    const size_t wtN   = (size_t)NPROJ * DIN;          // 1.18 M ush
    const size_t pN    = (size_t)NBATCH * SEQ * NPROJ; // 12.58 M ush
    const size_t xN    = (size_t)NBATCH * SEQ * DIN;   // 6.29 M ush
    const size_t trigN = (size_t)SEQ * 32 * 2;         // 32 K floats
    unsigned short* Wt = (unsigned short*)d_ws;
    unsigned short* P  = Wt + wtN;
    float* trig        = (float*)(P + pN);
    unsigned short* Xb = (unsigned short*)(trig + trigN);
    const bool pre = ws_size >= (wtN + pN + xN) * sizeof(unsigned short)
                               + trigN * sizeof(float);

    const int xblocks = (int)(xN / 1024);    // 6144
    k_prep<<<pre ? (352 + xblocks) : 352, 256, 0, stream>>>(x, Xb, W, Wt, trig);
    if (pre) {
        k_gemm<true><<<dim3(NPROJ / 128, (NBATCH * SEQ) / 128), 256, 0, stream>>>(
            x, Xb, Wt, bias, trig, P);
    } else {
        k_gemm<false><<<dim3(NPROJ / 128, (NBATCH * SEQ) / 128), 256, 0, stream>>>(
            x, nullptr, Wt, bias, trig, P);
    }
    k_attn<<<dim3(4, NHEAD, NBATCH), 256, 0, stream>>>(P, mask, out);
}